// Round 8
// baseline (413.200 us; speedup 1.0000x reference)
//
#include <hip/hip_runtime.h>

#define D 64
#define WQ_BITS 15
#define WQ_MAX 32767.0f
#define NSHARDS 8
#define SCB 4096        // scatter role blocks (8 shards x 512 slices; r1-verified)
#define CAP32 32        // bucket capacity (deg~Poisson(16); P(>32)~1e-4)

typedef int    int4v    __attribute__((ext_vector_type(4)));
typedef float  float4v  __attribute__((ext_vector_type(4)));

__device__ __forceinline__ ushort f2bf(float x) {
    unsigned u = __float_as_uint(x);
    unsigned r = (u + 0x7fff + ((u >> 16) & 1)) >> 16;  // round-to-nearest-even
    return (ushort)r;
}
__device__ __forceinline__ float bf2f(ushort u) {
    return __uint_as_float(((unsigned)u) << 16);
}

// ---------------------------------------------------------------------------
// W pre-transpose: wt2[k*128 + j*2 + {0,1}] = {W[j][k], W[j][64+k]}.
// 32KB table; makes the gemm role's W reads coalesced float2 and LDS-free.
__global__ __launch_bounds__(256) void wt2_kernel(
    const float* __restrict__ W, float* __restrict__ wt2)
{
    int idx = blockIdx.x * 256 + threadIdx.x;
    if (idx < 64 * 64) {
        int j = idx & 63;
        int k = idx >> 6;
        wt2[k * 128 + j * 2]     = W[j * 128 + k];
        wt2[k * 128 + j * 2 + 1] = W[j * 128 + 64 + k];
    }
}

// ---------------------------------------------------------------------------
// Round-17 combined kernel, ZERO LDS (r7 post-mortem: static 48KB LDS applied
// to scatter-role blocks too -> 3 blocks/CU -> scatter 78->~125us; overlap
// mechanism fine, LDS was the killer).
//   blocks [0, gemmB)    : wave-per-node matvec out=b+h@W1^T, g=bf16(h@W2^T)
//                          (1 shfl + 1 L1-hot float2 wt2 load + 2 FMA per k)
//   blocks [gemmB,+SCB)  : r1-verified shard scatter (atomic-latency-bound,
//                          VALU 6% idle -> gemm waves fill the bubbles)
// Coherence ledger: node-sharded scatter keeps each pairs row single-XCD-
// dirty (r2 cross-XCD plain stores corrupt; r3 agent-scope = 64B write-thru;
// r4 XCD-partition = L2 churn).
__global__ __launch_bounds__(256) void combined_kernel(
    const int* __restrict__ src, const int* __restrict__ dst,
    const float* __restrict__ w, int* __restrict__ cursor,
    unsigned* __restrict__ ovBits, unsigned* __restrict__ pairs,
    const float* __restrict__ h, const float* __restrict__ wt2,
    const float* __restrict__ b, float* __restrict__ out,
    ushort* __restrict__ g, int E, int N, int gemmB)
{
    int tid = threadIdx.x;
    if ((int)blockIdx.x < gemmB) {
        // ---------------- GEMM role (LDS-free matvec) ----------------
        int lane = tid & 63;
        int wv   = tid >> 6;
        float bj = b[lane];
        int stride = gemmB * 4;
        for (int n = blockIdx.x * 4 + wv; n < N; n += stride) {
            float hreg = h[(size_t)n * D + lane];
            float accS = bj, accG = 0.f;
            #pragma unroll 8
            for (int k = 0; k < 64; ++k) {
                float xk = __shfl(hreg, k, 64);
                float2 wv2 = *(const float2*)&wt2[k * 128 + lane * 2];
                accS += xk * wv2.x;
                accG += xk * wv2.y;
            }
            out[(size_t)n * D + lane] = accS;
            g[(size_t)n * D + lane] = f2bf(accG);
        }
    } else {
        // ---------------- scatter role (r1-verified body) ----------------
        int bid     = blockIdx.x - gemmB;
        int shard   = bid & (NSHARDS - 1);
        int slice   = bid >> 3;
        int nSlices = SCB >> 3;
        int n8 = (N + NSHARDS - 1) / NSHARDS;
        int lo = shard * n8;
        int hi = min(N, lo + n8);

        int e4 = E >> 2;
        for (int gi = slice * 256 + tid; gi < e4; gi += nSlices * 256) {
            int e0 = gi * 4;
            int4v   d4 = __builtin_nontemporal_load((const int4v*)&dst[e0]);
            int4v   s4 = __builtin_nontemporal_load((const int4v*)&src[e0]);
            float4v w4 = __builtin_nontemporal_load((const float4v*)&w[e0]);
            #pragma unroll
            for (int i = 0; i < 4; ++i) {
                int d = d4[i];
                if (d >= lo && d < hi) {
                    int e = e0 + i;
                    int pos = atomicAdd(&cursor[d], 1);
                    if (pos < CAP32) {
                        float wv = fminf(fmaxf(w4[i], 0.f), 1.f);
                        unsigned wq = (unsigned)(wv * WQ_MAX + 0.5f);
                        pairs[(size_t)d * CAP32 + pos] =
                            ((unsigned)s4[i] << WQ_BITS) | wq;
                    } else {
                        atomicOr(&ovBits[e >> 5], 1u << (e & 31));
                    }
                }
            }
        }
        for (int e = e4 * 4 + slice * 256 + tid; e < E; e += nSlices * 256) {
            int d = dst[e];
            if (d >= lo && d < hi) {
                int pos = atomicAdd(&cursor[d], 1);
                if (pos < CAP32) {
                    float wv = fminf(fmaxf(w[e], 0.f), 1.f);
                    unsigned wq = (unsigned)(wv * WQ_MAX + 0.5f);
                    pairs[(size_t)d * CAP32 + pos] =
                        ((unsigned)src[e] << WQ_BITS) | wq;
                } else {
                    atomicOr(&ovBits[e >> 5], 1u << (e & 31));
                }
            }
        }
    }
}

// ---------------------------------------------------------------------------
// Round-17 final agg, TWO nodes per wave (r7 analysis: 119us at 805GB/s, low
// VALU -> latency-bound; lanes 32-63 carried no codes). Lanes 0-31 hold node
// A's pair codes, 32-63 node B's -> 32 outstanding gathers/round (2x MLP),
// half the waves. Guarded gathers clamp src to 0 (g[0] is a safe hot row).
__global__ __launch_bounds__(256) void final_agg2_kernel(
    const ushort* __restrict__ g, const unsigned* __restrict__ pairs,
    const int* __restrict__ cursor, float* __restrict__ out, int N)
{
    int wave = threadIdx.x >> 6;
    int lane = threadIdx.x & 63;
    int p = blockIdx.x * 4 + wave;   // node-pair index
    int n0 = p * 2;
    if (n0 >= N) return;
    bool hasB = (n0 + 1) < N;
    int half = lane >> 5;
    int sl   = lane & 31;
    int nh   = n0 + half;            // node whose codes this lane carries

    int cnt_h = (nh < N) ? cursor[nh] : 0;
    unsigned mycode = (nh < N) ? pairs[(size_t)nh * CAP32 + sl] : 0u;
    int cntA = min(__shfl(cnt_h, 0, 64), CAP32);
    int cntB = min(__shfl(cnt_h, 32, 64), CAP32);

    float accA = out[(size_t)n0 * D + lane];
    float accB = hasB ? out[(size_t)(n0 + 1) * D + lane] : 0.f;
    const float wscale = 1.0f / WQ_MAX;

    int cmax = max(cntA, cntB);
    for (int j = 0; j < cmax; j += 16) {
        unsigned cA[16], cB[16];
        float vA[16], vB[16];
        #pragma unroll
        for (int u = 0; u < 16; ++u) {
            cA[u] = __shfl(mycode, j + u, 64);
            cB[u] = __shfl(mycode, 32 + j + u, 64);
        }
        #pragma unroll
        for (int u = 0; u < 16; ++u) {
            int sA = (j + u < cntA) ? (int)(cA[u] >> WQ_BITS) : 0;
            int sB = (j + u < cntB) ? (int)(cB[u] >> WQ_BITS) : 0;
            vA[u] = bf2f(g[(size_t)sA * D + lane]);
            vB[u] = bf2f(g[(size_t)sB * D + lane]);
        }
        #pragma unroll
        for (int u = 0; u < 16; ++u) {
            if (j + u < cntA)
                accA += (float)(cA[u] & 0x7fffu) * wscale * vA[u];
            if (j + u < cntB)
                accB += (float)(cB[u] & 0x7fffu) * wscale * vB[u];
        }
    }
    out[(size_t)n0 * D + lane] = accA;
    if (hasB) out[(size_t)(n0 + 1) * D + lane] = accB;
}

// ---------------------------------------------------------------------------
// Overflow cleanup — r0-r3 per-THREAD word scan (~3 dependent loads/thread).
// (r5/r6 hidden regression: per-WAVE scan serialized ~195 loads -> ~125us.)
__global__ __launch_bounds__(256) void overflow_kernel(
    const unsigned* __restrict__ ovBits, const int* __restrict__ src,
    const int* __restrict__ dst, const float* __restrict__ w,
    const ushort* __restrict__ g, float* __restrict__ out, int numWords)
{
    int idx = blockIdx.x * 256 + threadIdx.x;
    for (int wi = idx; wi < numWords; wi += gridDim.x * 256) {
        unsigned bits = ovBits[wi];
        while (bits) {
            int bit = __ffs(bits) - 1;
            bits &= bits - 1;
            int e = wi * 32 + bit;
            int s = src[e], d = dst[e];
            float wv = w[e];
            for (int f = 0; f < D; ++f)
                atomicAdd(&out[(size_t)d * D + f], wv * bf2f(g[(size_t)s * D + f]));
        }
    }
}

// ---------------------------------------------------------------------------
// Fallback path (small ws / big N): round-1 kernels, known-good.
__global__ __launch_bounds__(256) void edge_scatter_kernel(
    const float* __restrict__ h, const float* __restrict__ w,
    const int* __restrict__ src, const int* __restrict__ dst,
    float* __restrict__ agg, int E)
{
    int e = blockIdx.x * 4 + (threadIdx.x >> 6);
    int lane = threadIdx.x & 63;
    if (e >= E) return;
    float val = w[e] * h[(size_t)src[e] * D + lane];
    atomicAdd(&agg[(size_t)dst[e] * D + lane], val);
}

__global__ __launch_bounds__(256) void out_linear_kernel(
    const float* __restrict__ h, const float* __restrict__ agg,
    const float* __restrict__ W, const float* __restrict__ b,
    float* __restrict__ out, int N)
{
    __shared__ float Wt[128 * 64];
    int lane = threadIdx.x & 63;
    int waveInBlock = threadIdx.x >> 6;
    int wavesPerBlock = blockDim.x >> 6;
    for (int idx = threadIdx.x; idx < 128 * 64; idx += blockDim.x) {
        int j = idx & 63;
        int k = idx >> 6;
        Wt[k * 64 + j] = W[j * 128 + k];
    }
    __syncthreads();
    float bj = b[lane];
    int wavesPerGrid = gridDim.x * wavesPerBlock;
    for (int n = blockIdx.x * wavesPerBlock + waveInBlock; n < N; n += wavesPerGrid) {
        float hreg = h[(size_t)n * D + lane];
        float areg = agg[(size_t)n * D + lane];
        float acc = bj;
        #pragma unroll
        for (int k = 0; k < 64; ++k) {
            float hk = __shfl(hreg, k, 64);
            float ak = __shfl(areg, k, 64);
            acc += hk * Wt[k * 64 + lane];
            acc += ak * Wt[(k + 64) * 64 + lane];
        }
        out[(size_t)n * D + lane] = acc;
    }
}

// ---------------------------------------------------------------------------
extern "C" void kernel_launch(void* const* d_in, const int* in_sizes, int n_in,
                              void* d_out, int out_size, void* d_ws, size_t ws_size,
                              hipStream_t stream) {
    const float* h   = (const float*)d_in[0];
    const float* w   = (const float*)d_in[1];
    const int*   src = (const int*)d_in[2];
    const int*   dst = (const int*)d_in[3];
    const float* W   = (const float*)d_in[4];
    const float* b   = (const float*)d_in[5];
    float* out = (float*)d_out;

    int N = in_sizes[0] / D;
    int E = in_sizes[1];
    int numWords = (E + 31) / 32;

    auto align256 = [](size_t x) { return (x + 255) & ~(size_t)255; };
    size_t cursorB = align256((size_t)N * 4);
    size_t ovB     = align256((size_t)numWords * 4);
    size_t pairsB  = align256((size_t)N * CAP32 * 4);
    size_t gB      = align256((size_t)N * D * 2);
    size_t wtB     = align256((size_t)64 * 128 * 4);
    size_t need = cursorB + ovB + pairsB + gB + wtB;

    if (ws_size >= need && N <= (1 << 17)) {
        char* p = (char*)d_ws;
        int*      cursor = (int*)p;       p += cursorB;
        unsigned* ovBits = (unsigned*)p;  p += ovB;
        unsigned* pairs  = (unsigned*)p;  p += pairsB;
        ushort*   g      = (ushort*)p;    p += gB;
        float*    wt2    = (float*)p;

        hipMemsetAsync(cursor, 0, cursorB + ovB, stream);
        wt2_kernel<<<16, 256, 0, stream>>>(W, wt2);

        int gemmB = 1024;   // 4096 gemm waves, ~24 nodes each, LDS-free
        combined_kernel<<<gemmB + SCB, 256, 0, stream>>>(
            src, dst, w, cursor, ovBits, pairs, h, wt2, b, out, g, E, N, gemmB);
        final_agg2_kernel<<<((N + 1) / 2 + 3) / 4, 256, 0, stream>>>(
            g, pairs, cursor, out, N);
        overflow_kernel<<<64, 256, 0, stream>>>(ovBits, src, dst, w, g, out,
                                                numWords);
    } else {
        float* agg = out;
        hipMemsetAsync(agg, 0, (size_t)N * D * 4, stream);
        edge_scatter_kernel<<<(E + 3) / 4, 256, 0, stream>>>(h, w, src, dst, agg, E);
        out_linear_kernel<<<2048, 256, 0, stream>>>(h, agg, W, b, out, N);
    }
}